// Round 2
// baseline (162.030 us; speedup 1.0000x reference)
//
#include <hip/hip_runtime.h>
#include <hip/hip_bf16.h>

#define C_DIM 256
#define B_SZ 32
#define NS 4096
#define NT_Z 256
#define TOPK_K 32
#define NWIN 64
#define WTOK 64

typedef __attribute__((ext_vector_type(8))) short short8;
typedef __attribute__((ext_vector_type(4))) float f32x4;

static __device__ inline unsigned short f2b(float f) {
  union { float f; unsigned int u; } x; x.f = f;
  unsigned int u = x.u;
  return (unsigned short)((u + 0x7FFFu + ((u >> 16) & 1u)) >> 16);
}
static __device__ inline float b2f(unsigned short h) {
  union { unsigned int u; float f; } x; x.u = ((unsigned int)h) << 16;
  return x.f;
}

// ---------------- kernel 1: weights f32 -> bf16  +  z_max  (merged) --------
__global__ void prep_kernel(const float* __restrict__ Wd, const float* __restrict__ Wu,
                            unsigned short* __restrict__ Wdb, unsigned short* __restrict__ Wub,
                            const float* __restrict__ z, float* __restrict__ zmax) {
  int blk = blockIdx.x;
  if (blk < 256) {
    int i = blk * 256 + threadIdx.x;   // 65536 elements each
    Wdb[i] = f2b(Wd[i]);
    Wub[i] = f2b(Wu[i]);
  } else {
    int b = blk - 256;
    int c = threadIdx.x;
    const float* p = z + (size_t)b * NT_Z * C_DIM + c;
    float m = p[0];
    for (int n = 1; n < NT_Z; ++n) m = fmaxf(m, p[(size_t)n * C_DIM]);
    zmax[b * C_DIM + c] = m;
  }
}

// ---------------- kernel 2: window scores ----------------
__global__ __launch_bounds__(256) void winscore_kernel(const float* __restrict__ x,
                                                       const float* __restrict__ zmax,
                                                       float* __restrict__ score) {
  int b = blockIdx.x >> 6;
  int w = blockIdx.x & 63;
  int wy = w >> 3, wx = w & 7;

  __shared__ float zs[C_DIM];
  zs[threadIdx.x] = zmax[b * C_DIM + threadIdx.x];
  __syncthreads();

  int wv = threadIdx.x >> 6;
  int ln = threadIdx.x & 63;

  float a0 = 0.f, a1 = 0.f, a2 = 0.f, a3 = 0.f;
  for (int t = 0; t < 16; ++t) {
    int tok = wv * 16 + t;
    int iy = tok >> 3, ix = tok & 7;
    int n = (wy * 8 + iy) * 64 + wx * 8 + ix;
    const float4 v = *(const float4*)(x + ((size_t)b * NS + n) * C_DIM + ln * 4);
    a0 += v.x; a1 += v.y; a2 += v.z; a3 += v.w;
  }
  const float4 z4 = ((const float4*)zs)[ln];
  float p = a0 * z4.x + a1 * z4.y + a2 * z4.z + a3 * z4.w;
  for (int off = 32; off >= 1; off >>= 1) p += __shfl_xor(p, off);

  __shared__ float wsum[4];
  if (ln == 0) wsum[wv] = p;
  __syncthreads();
  if (threadIdx.x == 0) score[blockIdx.x] = wsum[0] + wsum[1] + wsum[2] + wsum[3];
}

// ---------------- kernel 3: fused topk-select + gather + GEMM1 + shift +
//                            GEMM2 + residual ----------------
// one block per (b, k).  Single 32 KB LDS buffer reused xe -> t.
// 4 waves; wave wv owns output channels [wv*64, wv*64+64).
// XOR swizzle: byte_in_row ^= (row & 7) << 4.
__global__ __launch_bounds__(256, 4) void fused_win(
    const float* __restrict__ x, const float* __restrict__ score,
    const unsigned short* __restrict__ Wdb, const unsigned short* __restrict__ Wub,
    const float* __restrict__ bd, const float* __restrict__ bu,
    float* __restrict__ out)
{
  __shared__ unsigned short buf[WTOK * C_DIM];  // 32 KB (xe, then t)
  __shared__ float sc[NWIN];
  __shared__ int wsel_s;

  const int bk = blockIdx.x;
  const int b = bk >> 5;
  const int kk = bk & 31;
  const int tid = threadIdx.x;

  // ---- in-block top-k rank select (reproduces jax.lax.top_k order) ----
  if (tid < NWIN) sc[tid] = score[b * NWIN + tid];
  __syncthreads();
  if (tid < NWIN) {
    float v = sc[tid];
    int rank = 0;
    #pragma unroll
    for (int j = 0; j < NWIN; ++j) {
      float sj = sc[j];
      rank += (sj > v) || (sj == v && j < tid);
    }
    if (rank == kk) wsel_s = tid;
  }
  __syncthreads();
  const int wsel = wsel_s;
  const int wy = wsel >> 3, wx = wsel & 7;

  // ---- stage xe (window tokens) as bf16, swizzled ----
  #pragma unroll
  for (int i = 0; i < 16; ++i) {
    int f = tid + i * 256;   // float4 id 0..4095
    int m = f >> 6, c4 = f & 63;
    int iy = m >> 3, ix = m & 7;
    int n = (wy * 8 + iy) * 64 + wx * 8 + ix;
    const float4 v = *(const float4*)(x + ((size_t)b * NS + n) * C_DIM + c4 * 4);
    ushort4 h;
    h.x = f2b(v.x); h.y = f2b(v.y); h.z = f2b(v.z); h.w = f2b(v.w);
    int byteoff = m * 512 + ((c4 * 8) ^ ((m & 7) << 4));
    *(ushort4*)((char*)buf + byteoff) = h;
  }
  __syncthreads();

  const int wv = tid >> 6;
  const int ln = tid & 63;
  const int lr = ln & 15;   // A-row / B-col / D-col
  const int lg = ln >> 4;   // k-subgroup

  const unsigned short* wdbase = Wdb + ((wv * 4) * 16 + lr) * C_DIM + lg * 8;
  const unsigned short* wubase = Wub + ((wv * 4) * 16 + lr) * C_DIM + lg * 8;

  // ---- GEMM1: t = xe @ Wd^T  (depth-1 weight prefetch) ----
  f32x4 acc[4][4];
  #pragma unroll
  for (int a = 0; a < 4; ++a)
    #pragma unroll
    for (int n2 = 0; n2 < 4; ++n2) acc[a][n2] = (f32x4){0.f, 0.f, 0.f, 0.f};

  {
    short8 bcur[4], bnxt[4];
    #pragma unroll
    for (int nt = 0; nt < 4; ++nt) bcur[nt] = *(const short8*)(wdbase + nt * 16 * C_DIM);
    #pragma unroll
    for (int ks = 0; ks < 8; ++ks) {
      if (ks < 7) {
        #pragma unroll
        for (int nt = 0; nt < 4; ++nt)
          bnxt[nt] = *(const short8*)(wdbase + nt * 16 * C_DIM + (ks + 1) * 32);
      }
      const int kb = ks * 64 + lg * 16;
      short8 af[4];
      #pragma unroll
      for (int mt = 0; mt < 4; ++mt) {
        int m = mt * 16 + lr;
        af[mt] = *(const short8*)((const char*)buf + m * 512 + (kb ^ ((m & 7) << 4)));
      }
      #pragma unroll
      for (int mt = 0; mt < 4; ++mt)
        #pragma unroll
        for (int nt = 0; nt < 4; ++nt)
          acc[mt][nt] = __builtin_amdgcn_mfma_f32_16x16x32_bf16(af[mt], bcur[nt], acc[mt][nt], 0, 0, 0);
      #pragma unroll
      for (int nt = 0; nt < 4; ++nt) bcur[nt] = bnxt[nt];
    }
  }
  __syncthreads();   // all xe reads done before t overwrites buf

  // ---- epilogue 1: t = acc + bd -> bf16 -> buf (swizzled) ----
  #pragma unroll
  for (int nt = 0; nt < 4; ++nt) {
    int o = (wv * 4 + nt) * 16 + lr;
    float bdv = bd[o];
    #pragma unroll
    for (int mt = 0; mt < 4; ++mt) {
      #pragma unroll
      for (int r = 0; r < 4; ++r) {
        int m = mt * 16 + lg * 4 + r;
        float v = acc[mt][nt][r] + bdv;
        *(unsigned short*)((char*)buf + m * 512 + ((o * 2) ^ ((m & 7) << 4))) = f2b(v);
      }
    }
  }
  __syncthreads();

  // ---- GEMM2: up = shift(t) @ Wu^T  (depth-1 weight prefetch) ----
  f32x4 acc2[4][4];
  #pragma unroll
  for (int a = 0; a < 4; ++a)
    #pragma unroll
    for (int n2 = 0; n2 < 4; ++n2) acc2[a][n2] = (f32x4){0.f, 0.f, 0.f, 0.f};

  {
    short8 bcur[4], bnxt[4];
    #pragma unroll
    for (int nt = 0; nt < 4; ++nt) bcur[nt] = *(const short8*)(wubase + nt * 16 * C_DIM);
    #pragma unroll
    for (int ks = 0; ks < 8; ++ks) {
      if (ks < 7) {
        #pragma unroll
        for (int nt = 0; nt < 4; ++nt)
          bnxt[nt] = *(const short8*)(wubase + nt * 16 * C_DIM + (ks + 1) * 32);
      }
      const int g = ks >> 1;              // channel group (64-wide), uniform per ks
      const int kb = ks * 64 + lg * 16;
      short8 af[4];
      #pragma unroll
      for (int mt = 0; mt < 4; ++mt) {
        int m = mt * 16 + lr;
        int iy = m >> 3, ix = m & 7;
        int ms; bool ok;
        if (g == 0)      { ok = (ix < 7); ms = m + 1; }
        else if (g == 1) { ok = (ix > 0); ms = m - 1; }
        else if (g == 2) { ok = (iy < 7); ms = m + 8; }
        else             { ok = (iy > 0); ms = m - 8; }
        short8 v = {0, 0, 0, 0, 0, 0, 0, 0};
        if (ok) v = *(const short8*)((const char*)buf + ms * 512 + (kb ^ ((ms & 7) << 4)));
        af[mt] = v;
      }
      #pragma unroll
      for (int mt = 0; mt < 4; ++mt)
        #pragma unroll
        for (int nt = 0; nt < 4; ++nt)
          acc2[mt][nt] = __builtin_amdgcn_mfma_f32_16x16x32_bf16(af[mt], bcur[nt], acc2[mt][nt], 0, 0, 0);
      #pragma unroll
      for (int nt = 0; nt < 4; ++nt) bcur[nt] = bnxt[nt];
    }
  }

  // ---- epilogue 2: out = x(f32 re-read) + up + bu ----
  const size_t obase = (size_t)bk * WTOK * C_DIM;
  #pragma unroll
  for (int nt = 0; nt < 4; ++nt) {
    int c = (wv * 4 + nt) * 16 + lr;
    float buv = bu[c];
    #pragma unroll
    for (int mt = 0; mt < 4; ++mt) {
      #pragma unroll
      for (int r = 0; r < 4; ++r) {
        int m = mt * 16 + lg * 4 + r;
        int n = (wy * 8 + (m >> 3)) * 64 + wx * 8 + (m & 7);
        float xr = x[((size_t)b * NS + n) * C_DIM + c];
        out[obase + (size_t)m * C_DIM + c] = xr + acc2[mt][nt][r] + buv;
      }
    }
  }
}

// ---------------- launch ----------------
extern "C" void kernel_launch(void* const* d_in, const int* in_sizes, int n_in,
                              void* d_out, int out_size, void* d_ws, size_t ws_size,
                              hipStream_t stream) {
  const float* z  = (const float*)d_in[0];
  const float* x  = (const float*)d_in[1];
  const float* Wd = (const float*)d_in[2];
  const float* bd = (const float*)d_in[3];
  const float* Wu = (const float*)d_in[4];
  const float* bu = (const float*)d_in[5];
  float* out = (float*)d_out;

  char* ws = (char*)d_ws;
  unsigned short* Wdb = (unsigned short*)(ws);            // 131072 B
  unsigned short* Wub = (unsigned short*)(ws + 131072);   // 131072 B
  float* zmax  = (float*)(ws + 262144);                   // 32 KB
  float* score = (float*)(ws + 294912);                   // 8 KB

  hipLaunchKernelGGL(prep_kernel, dim3(288), dim3(256), 0, stream, Wd, Wu, Wdb, Wub, z, zmax);
  hipLaunchKernelGGL(winscore_kernel, dim3(B_SZ * NWIN), dim3(256), 0, stream, x, zmax, score);
  hipLaunchKernelGGL(fused_win, dim3(B_SZ * TOPK_K), dim3(256), 0, stream,
                     x, score, Wdb, Wub, bd, bu, out);
}

// Round 3
// 99.319 us; speedup vs baseline: 1.6314x; 1.6314x over previous
//
#include <hip/hip_runtime.h>
#include <hip/hip_bf16.h>

#define C_DIM 256
#define B_SZ 32
#define NS 4096
#define NT_Z 256
#define TOPK_K 32
#define NWIN 64
#define WTOK 64

typedef __attribute__((ext_vector_type(8))) short short8;
typedef __attribute__((ext_vector_type(4))) float f32x4;

static __device__ inline unsigned short f2b(float f) {
  union { float f; unsigned int u; } x; x.f = f;
  unsigned int u = x.u;
  return (unsigned short)((u + 0x7FFFu + ((u >> 16) & 1u)) >> 16);
}
static __device__ inline float b2f(unsigned int h16) {   // low 16 bits = bf16
  union { unsigned int u; float f; } x; x.u = h16 << 16;
  return x.f;
}

// ---------------- kernel 1: weights f32->bf16 (vectorized) + z_max partials -
// blocks 0..63   : weight conversion, float4 granularity
// blocks 64..319 : z_max partial over 32-row chunks -> zpart[b*8+ch][c]
__global__ void prep_kernel(const float* __restrict__ Wd, const float* __restrict__ Wu,
                            unsigned short* __restrict__ Wdb, unsigned short* __restrict__ Wub,
                            const float* __restrict__ z, float* __restrict__ zpart) {
  int blk = blockIdx.x;
  if (blk < 64) {
    int i = blk * 256 + threadIdx.x;     // float4 id, 16384 per matrix
    float4 a = ((const float4*)Wd)[i];
    float4 c = ((const float4*)Wu)[i];
    ushort4 ha, hc;
    ha.x = f2b(a.x); ha.y = f2b(a.y); ha.z = f2b(a.z); ha.w = f2b(a.w);
    hc.x = f2b(c.x); hc.y = f2b(c.y); hc.z = f2b(c.z); hc.w = f2b(c.w);
    ((ushort4*)Wdb)[i] = ha;
    ((ushort4*)Wub)[i] = hc;
  } else {
    int i = blk - 64;                    // 0..255
    int b = i >> 3, ch = i & 7;
    int c = threadIdx.x;
    const float* p = z + ((size_t)b * NT_Z + ch * 32) * C_DIM + c;
    float m = p[0];
    for (int n = 1; n < 32; ++n) m = fmaxf(m, p[(size_t)n * C_DIM]);
    zpart[(size_t)i * C_DIM + c] = m;
  }
}

// ---------------- kernel 2: window scores (+ zmax final reduce) -------------
__global__ __launch_bounds__(256) void winscore_kernel(const float* __restrict__ x,
                                                       const float* __restrict__ zpart,
                                                       float* __restrict__ score) {
  int b = blockIdx.x >> 6;
  int w = blockIdx.x & 63;
  int wy = w >> 3, wx = w & 7;

  __shared__ float zs[C_DIM];
  {
    float m = zpart[(size_t)(b * 8) * C_DIM + threadIdx.x];
    #pragma unroll
    for (int ch = 1; ch < 8; ++ch)
      m = fmaxf(m, zpart[(size_t)(b * 8 + ch) * C_DIM + threadIdx.x]);
    zs[threadIdx.x] = m;
  }
  __syncthreads();

  int wv = threadIdx.x >> 6;
  int ln = threadIdx.x & 63;

  float a0 = 0.f, a1 = 0.f, a2 = 0.f, a3 = 0.f;
  for (int t = 0; t < 16; ++t) {
    int tok = wv * 16 + t;
    int iy = tok >> 3, ix = tok & 7;
    int n = (wy * 8 + iy) * 64 + wx * 8 + ix;
    const float4 v = *(const float4*)(x + ((size_t)b * NS + n) * C_DIM + ln * 4);
    a0 += v.x; a1 += v.y; a2 += v.z; a3 += v.w;
  }
  const float4 z4 = ((const float4*)zs)[ln];
  float p = a0 * z4.x + a1 * z4.y + a2 * z4.z + a3 * z4.w;
  for (int off = 32; off >= 1; off >>= 1) p += __shfl_xor(p, off);

  __shared__ float wsum[4];
  if (ln == 0) wsum[wv] = p;
  __syncthreads();
  if (threadIdx.x == 0) score[blockIdx.x] = wsum[0] + wsum[1] + wsum[2] + wsum[3];
}

// ---------------- kernel 3: fused topk + gather + GEMM1 + shift + GEMM2 ----
// one block per (b, k).  Single 32 KB LDS buffer (xe, then t).
// Residual xe captured into 32 packed VGPRs after GEMM1, folded into acc2 init.
// XOR swizzle: byte_in_row ^= (row & 7) << 4.
__global__ __launch_bounds__(256, 4) void fused_win(
    const float* __restrict__ x, const float* __restrict__ score,
    const unsigned short* __restrict__ Wdb, const unsigned short* __restrict__ Wub,
    const float* __restrict__ bd, const float* __restrict__ bu,
    float* __restrict__ out)
{
  __shared__ unsigned short buf[WTOK * C_DIM];  // 32 KB (xe, then t)
  __shared__ float sc[NWIN];
  __shared__ int wsel_s;

  const int bk = blockIdx.x;
  const int b = bk >> 5;
  const int kk = bk & 31;
  const int tid = threadIdx.x;

  // ---- in-block top-k rank select (reproduces jax.lax.top_k order) ----
  if (tid < NWIN) sc[tid] = score[b * NWIN + tid];
  __syncthreads();
  if (tid < NWIN) {
    float v = sc[tid];
    int rank = 0;
    #pragma unroll
    for (int j = 0; j < NWIN; ++j) {
      float sj = sc[j];
      rank += (sj > v) || (sj == v && j < tid);
    }
    if (rank == kk) wsel_s = tid;
  }
  __syncthreads();
  const int wsel = wsel_s;
  const int wy = wsel >> 3, wx = wsel & 7;

  // ---- stage xe (window tokens) as bf16, swizzled ----
  #pragma unroll
  for (int i = 0; i < 16; ++i) {
    int f = tid + i * 256;   // float4 id 0..4095
    int m = f >> 6, c4 = f & 63;
    int iy = m >> 3, ix = m & 7;
    int n = (wy * 8 + iy) * 64 + wx * 8 + ix;
    const float4 v = *(const float4*)(x + ((size_t)b * NS + n) * C_DIM + c4 * 4);
    ushort4 h;
    h.x = f2b(v.x); h.y = f2b(v.y); h.z = f2b(v.z); h.w = f2b(v.w);
    int byteoff = m * 512 + ((c4 * 8) ^ ((m & 7) << 4));
    *(ushort4*)((char*)buf + byteoff) = h;
  }
  __syncthreads();

  const int wv = tid >> 6;
  const int ln = tid & 63;
  const int lr = ln & 15;   // A-row / B-col / D-col
  const int lg = ln >> 4;   // k-subgroup

  const unsigned short* wdbase = Wdb + ((wv * 4) * 16 + lr) * C_DIM + lg * 8;
  const unsigned short* wubase = Wub + ((wv * 4) * 16 + lr) * C_DIM + lg * 8;

  // ---- GEMM1: t = xe @ Wd^T ----
  f32x4 acc[4][4];
  #pragma unroll
  for (int a = 0; a < 4; ++a)
    #pragma unroll
    for (int n2 = 0; n2 < 4; ++n2) acc[a][n2] = (f32x4){0.f, 0.f, 0.f, 0.f};

  #pragma unroll
  for (int ks = 0; ks < 8; ++ks) {
    const int kb = ks * 64 + lg * 16;
    short8 af[4];
    #pragma unroll
    for (int mt = 0; mt < 4; ++mt) {
      int m = mt * 16 + lr;
      af[mt] = *(const short8*)((const char*)buf + m * 512 + (kb ^ ((m & 7) << 4)));
    }
    short8 bf[4];
    #pragma unroll
    for (int nt = 0; nt < 4; ++nt)
      bf[nt] = *(const short8*)(wdbase + nt * 16 * C_DIM + ks * 32);
    #pragma unroll
    for (int mt = 0; mt < 4; ++mt)
      #pragma unroll
      for (int nt = 0; nt < 4; ++nt)
        acc[mt][nt] = __builtin_amdgcn_mfma_f32_16x16x32_bf16(af[mt], bf[nt], acc[mt][nt], 0, 0, 0);
  }

  // ---- capture residual xe (MFMA C/D layout) into packed regs ----
  // res[mt][nt][j] packs rows (lg*4+2j, lg*4+2j+1) at col c = wv*64+nt*16+lr
  unsigned int res[4][4][2];
  #pragma unroll
  for (int mt = 0; mt < 4; ++mt) {
    #pragma unroll
    for (int nt = 0; nt < 4; ++nt) {
      int c = wv * 64 + nt * 16 + lr;
      #pragma unroll
      for (int j = 0; j < 2; ++j) {
        int m0 = mt * 16 + lg * 4 + 2 * j;
        unsigned int lo = *(const unsigned short*)((const char*)buf + m0 * 512 + ((c * 2) ^ ((m0 & 7) << 4)));
        unsigned int hi = *(const unsigned short*)((const char*)buf + (m0 + 1) * 512 + ((c * 2) ^ (((m0 + 1) & 7) << 4)));
        res[mt][nt][j] = lo | (hi << 16);
      }
    }
  }
  __syncthreads();   // all xe reads done before t overwrites buf

  // ---- epilogue 1: t = acc + bd -> bf16 -> buf (swizzled) ----
  #pragma unroll
  for (int nt = 0; nt < 4; ++nt) {
    int o = wv * 64 + nt * 16 + lr;
    float bdv = bd[o];
    #pragma unroll
    for (int mt = 0; mt < 4; ++mt) {
      #pragma unroll
      for (int r = 0; r < 4; ++r) {
        int m = mt * 16 + lg * 4 + r;
        float v = acc[mt][nt][r] + bdv;
        *(unsigned short*)((char*)buf + m * 512 + ((o * 2) ^ ((m & 7) << 4))) = f2b(v);
      }
    }
  }
  __syncthreads();

  // ---- GEMM2: up = shift(t) @ Wu^T ; acc2 init = xe + bu ----
  f32x4 acc2[4][4];
  {
    float buv[4];
    #pragma unroll
    for (int nt = 0; nt < 4; ++nt) buv[nt] = bu[wv * 64 + nt * 16 + lr];
    #pragma unroll
    for (int mt = 0; mt < 4; ++mt) {
      #pragma unroll
      for (int nt = 0; nt < 4; ++nt) {
        acc2[mt][nt][0] = b2f(res[mt][nt][0] & 0xffffu) + buv[nt];
        acc2[mt][nt][1] = b2f(res[mt][nt][0] >> 16)     + buv[nt];
        acc2[mt][nt][2] = b2f(res[mt][nt][1] & 0xffffu) + buv[nt];
        acc2[mt][nt][3] = b2f(res[mt][nt][1] >> 16)     + buv[nt];
      }
    }
  }

  #pragma unroll
  for (int ks = 0; ks < 8; ++ks) {
    const int g = ks >> 1;              // channel group (64-wide), uniform per ks
    const int kb = ks * 64 + lg * 16;
    short8 af[4];
    #pragma unroll
    for (int mt = 0; mt < 4; ++mt) {
      int m = mt * 16 + lr;
      int iy = m >> 3, ix = m & 7;
      int ms; bool ok;
      if (g == 0)      { ok = (ix < 7); ms = m + 1; }
      else if (g == 1) { ok = (ix > 0); ms = m - 1; }
      else if (g == 2) { ok = (iy < 7); ms = m + 8; }
      else             { ok = (iy > 0); ms = m - 8; }
      short8 v = {0, 0, 0, 0, 0, 0, 0, 0};
      if (ok) v = *(const short8*)((const char*)buf + ms * 512 + (kb ^ ((ms & 7) << 4)));
      af[mt] = v;
    }
    short8 bf[4];
    #pragma unroll
    for (int nt = 0; nt < 4; ++nt)
      bf[nt] = *(const short8*)(wubase + nt * 16 * C_DIM + ks * 32);
    #pragma unroll
    for (int mt = 0; mt < 4; ++mt)
      #pragma unroll
      for (int nt = 0; nt < 4; ++nt)
        acc2[mt][nt] = __builtin_amdgcn_mfma_f32_16x16x32_bf16(af[mt], bf[nt], acc2[mt][nt], 0, 0, 0);
  }

  // ---- epilogue 2: out = acc2 (already includes xe + bu) ----
  const size_t obase = (size_t)bk * WTOK * C_DIM;
  #pragma unroll
  for (int nt = 0; nt < 4; ++nt) {
    int c = wv * 64 + nt * 16 + lr;
    #pragma unroll
    for (int mt = 0; mt < 4; ++mt) {
      #pragma unroll
      for (int r = 0; r < 4; ++r) {
        int m = mt * 16 + lg * 4 + r;
        out[obase + (size_t)m * C_DIM + c] = acc2[mt][nt][r];
      }
    }
  }
}

// ---------------- launch ----------------
extern "C" void kernel_launch(void* const* d_in, const int* in_sizes, int n_in,
                              void* d_out, int out_size, void* d_ws, size_t ws_size,
                              hipStream_t stream) {
  const float* z  = (const float*)d_in[0];
  const float* x  = (const float*)d_in[1];
  const float* Wd = (const float*)d_in[2];
  const float* bd = (const float*)d_in[3];
  const float* Wu = (const float*)d_in[4];
  const float* bu = (const float*)d_in[5];
  float* out = (float*)d_out;

  char* ws = (char*)d_ws;
  unsigned short* Wdb = (unsigned short*)(ws);            // 131072 B
  unsigned short* Wub = (unsigned short*)(ws + 131072);   // 131072 B
  float* zpart = (float*)(ws + 262144);                   // 256 KB (32*8*256 f32)
  float* score = (float*)(ws + 524288);                   // 8 KB

  hipLaunchKernelGGL(prep_kernel, dim3(320), dim3(256), 0, stream, Wd, Wu, Wdb, Wub, z, zpart);
  hipLaunchKernelGGL(winscore_kernel, dim3(B_SZ * NWIN), dim3(256), 0, stream, x, zpart, score);
  hipLaunchKernelGGL(fused_win, dim3(B_SZ * TOPK_K), dim3(256), 0, stream,
                     x, score, Wdb, Wub, bd, bu, out);
}

// Round 4
// 95.344 us; speedup vs baseline: 1.6994x; 1.0417x over previous
//
#include <hip/hip_runtime.h>
#include <hip/hip_bf16.h>

#define C_DIM 256
#define B_SZ 32
#define NS 4096
#define NT_Z 256
#define TOPK_K 32
#define NWIN 64
#define WTOK 64

typedef __attribute__((ext_vector_type(8))) short short8;
typedef __attribute__((ext_vector_type(4))) float f32x4;

static __device__ inline unsigned short f2b(float f) {
  union { float f; unsigned int u; } x; x.f = f;
  unsigned int u = x.u;
  return (unsigned short)((u + 0x7FFFu + ((u >> 16) & 1u)) >> 16);
}
static __device__ inline float b2f(unsigned int h16) {   // low 16 bits = bf16
  union { unsigned int u; float f; } x; x.u = h16 << 16;
  return x.f;
}

// ---------------- kernel 1: weights f32->bf16 (vectorized) + z_max partials -
__global__ void prep_kernel(const float* __restrict__ Wd, const float* __restrict__ Wu,
                            unsigned short* __restrict__ Wdb, unsigned short* __restrict__ Wub,
                            const float* __restrict__ z, float* __restrict__ zpart) {
  int blk = blockIdx.x;
  if (blk < 64) {
    int i = blk * 256 + threadIdx.x;     // float4 id, 16384 per matrix
    float4 a = ((const float4*)Wd)[i];
    float4 c = ((const float4*)Wu)[i];
    ushort4 ha, hc;
    ha.x = f2b(a.x); ha.y = f2b(a.y); ha.z = f2b(a.z); ha.w = f2b(a.w);
    hc.x = f2b(c.x); hc.y = f2b(c.y); hc.z = f2b(c.z); hc.w = f2b(c.w);
    ((ushort4*)Wdb)[i] = ha;
    ((ushort4*)Wub)[i] = hc;
  } else {
    int i = blk - 64;                    // 0..255
    int b = i >> 3, ch = i & 7;
    int c = threadIdx.x;
    const float* p = z + ((size_t)b * NT_Z + ch * 32) * C_DIM + c;
    float m = p[0];
    for (int n = 1; n < 32; ++n) m = fmaxf(m, p[(size_t)n * C_DIM]);
    zpart[(size_t)i * C_DIM + c] = m;
  }
}

// ---------------- kernel 2: window scores (+ zmax final reduce) -------------
__global__ __launch_bounds__(256) void winscore_kernel(const float* __restrict__ x,
                                                       const float* __restrict__ zpart,
                                                       float* __restrict__ score) {
  int b = blockIdx.x >> 6;
  int w = blockIdx.x & 63;
  int wy = w >> 3, wx = w & 7;

  __shared__ float zs[C_DIM];
  {
    float m = zpart[(size_t)(b * 8) * C_DIM + threadIdx.x];
    #pragma unroll
    for (int ch = 1; ch < 8; ++ch)
      m = fmaxf(m, zpart[(size_t)(b * 8 + ch) * C_DIM + threadIdx.x]);
    zs[threadIdx.x] = m;
  }
  __syncthreads();

  int wv = threadIdx.x >> 6;
  int ln = threadIdx.x & 63;

  float a0 = 0.f, a1 = 0.f, a2 = 0.f, a3 = 0.f;
  for (int t = 0; t < 16; ++t) {
    int tok = wv * 16 + t;
    int iy = tok >> 3, ix = tok & 7;
    int n = (wy * 8 + iy) * 64 + wx * 8 + ix;
    const float4 v = *(const float4*)(x + ((size_t)b * NS + n) * C_DIM + ln * 4);
    a0 += v.x; a1 += v.y; a2 += v.z; a3 += v.w;
  }
  const float4 z4 = ((const float4*)zs)[ln];
  float p = a0 * z4.x + a1 * z4.y + a2 * z4.z + a3 * z4.w;
  for (int off = 32; off >= 1; off >>= 1) p += __shfl_xor(p, off);

  __shared__ float wsum[4];
  if (ln == 0) wsum[wv] = p;
  __syncthreads();
  if (threadIdx.x == 0) score[blockIdx.x] = wsum[0] + wsum[1] + wsum[2] + wsum[3];
}

// ---------------- kernel 3: fused topk + gather + GEMM1 + shift + GEMM2 ----
// one block per (b, k).  Single 32 KB LDS buffer (xe, then t).
// __launch_bounds__(256,3): combined reg cap ~170 (64 AGPR acc + ~106 VGPR)
// -- enough ILP for pipelined loads, 3 blocks/CU.
// XOR swizzle: byte_in_row ^= (row & 7) << 4.
__global__ __launch_bounds__(256, 3) void fused_win(
    const float* __restrict__ x, const float* __restrict__ score,
    const unsigned short* __restrict__ Wdb, const unsigned short* __restrict__ Wub,
    const float* __restrict__ bd, const float* __restrict__ bu,
    float* __restrict__ out)
{
  __shared__ unsigned short buf[WTOK * C_DIM];  // 32 KB (xe, then t)
  __shared__ float sc[NWIN];
  __shared__ int wsel_s;

  const int bk = blockIdx.x;
  const int b = bk >> 5;
  const int kk = bk & 31;
  const int tid = threadIdx.x;

  // ---- in-block top-k rank select (reproduces jax.lax.top_k order) ----
  if (tid < NWIN) sc[tid] = score[b * NWIN + tid];
  __syncthreads();
  if (tid < NWIN) {
    float v = sc[tid];
    int rank = 0;
    #pragma unroll
    for (int j = 0; j < NWIN; ++j) {
      float sj = sc[j];
      rank += (sj > v) || (sj == v && j < tid);
    }
    if (rank == kk) wsel_s = tid;
  }
  __syncthreads();
  const int wsel = wsel_s;
  const int wy = wsel >> 3, wx = wsel & 7;

  // ---- stage xe (window tokens) as bf16, swizzled ----
  {
    const int c4 = tid & 63;        // float4 column, constant per thread
    const int m0 = tid >> 6;        // starting row
    const float* xb = x + (size_t)b * NS * C_DIM + c4 * 4;
    #pragma unroll 4
    for (int i = 0; i < 16; ++i) {
      int m = m0 + i * 4;
      int n = (wy * 8 + (m >> 3)) * 64 + wx * 8 + (m & 7);
      const float4 v = *(const float4*)(xb + (size_t)n * C_DIM);
      ushort4 h;
      h.x = f2b(v.x); h.y = f2b(v.y); h.z = f2b(v.z); h.w = f2b(v.w);
      int byteoff = m * 512 + ((c4 * 8) ^ ((m & 7) << 4));
      *(ushort4*)((char*)buf + byteoff) = h;
    }
  }
  __syncthreads();

  const int wv = tid >> 6;
  const int ln = tid & 63;
  const int lr = ln & 15;   // A-row / B-col / D-col
  const int lg = ln >> 4;   // k-subgroup

  const unsigned short* wdbase = Wdb + ((wv * 4) * 16 + lr) * C_DIM + lg * 8;
  const unsigned short* wubase = Wub + ((wv * 4) * 16 + lr) * C_DIM + lg * 8;

  // ---- GEMM1: t = xe @ Wd^T ----
  f32x4 acc[4][4];
  #pragma unroll
  for (int a = 0; a < 4; ++a)
    #pragma unroll
    for (int n2 = 0; n2 < 4; ++n2) acc[a][n2] = (f32x4){0.f, 0.f, 0.f, 0.f};

  #pragma unroll 2
  for (int ks = 0; ks < 8; ++ks) {
    short8 bf[4];
    #pragma unroll
    for (int nt = 0; nt < 4; ++nt)
      bf[nt] = *(const short8*)(wdbase + nt * 16 * C_DIM + ks * 32);
    const int kb = ks * 64 + lg * 16;
    short8 af[4];
    #pragma unroll
    for (int mt = 0; mt < 4; ++mt) {
      int m = mt * 16 + lr;
      af[mt] = *(const short8*)((const char*)buf + m * 512 + (kb ^ ((m & 7) << 4)));
    }
    #pragma unroll
    for (int mt = 0; mt < 4; ++mt)
      #pragma unroll
      for (int nt = 0; nt < 4; ++nt)
        acc[mt][nt] = __builtin_amdgcn_mfma_f32_16x16x32_bf16(af[mt], bf[nt], acc[mt][nt], 0, 0, 0);
  }

  // ---- capture residual xe (MFMA C/D layout) into packed regs ----
  unsigned int res[4][4][2];
  #pragma unroll
  for (int mt = 0; mt < 4; ++mt) {
    #pragma unroll
    for (int nt = 0; nt < 4; ++nt) {
      int c = wv * 64 + nt * 16 + lr;
      #pragma unroll
      for (int j = 0; j < 2; ++j) {
        int m0 = mt * 16 + lg * 4 + 2 * j;
        unsigned int lo = *(const unsigned short*)((const char*)buf + m0 * 512 + ((c * 2) ^ ((m0 & 7) << 4)));
        unsigned int hi = *(const unsigned short*)((const char*)buf + (m0 + 1) * 512 + ((c * 2) ^ (((m0 + 1) & 7) << 4)));
        res[mt][nt][j] = lo | (hi << 16);
      }
    }
  }
  __syncthreads();   // all xe reads done before t overwrites buf

  // ---- epilogue 1: t = acc + bd -> bf16 -> buf (swizzled) ----
  #pragma unroll
  for (int nt = 0; nt < 4; ++nt) {
    int o = wv * 64 + nt * 16 + lr;
    float bdv = bd[o];
    #pragma unroll
    for (int mt = 0; mt < 4; ++mt) {
      #pragma unroll
      for (int r = 0; r < 4; ++r) {
        int m = mt * 16 + lg * 4 + r;
        float v = acc[mt][nt][r] + bdv;
        *(unsigned short*)((char*)buf + m * 512 + ((o * 2) ^ ((m & 7) << 4))) = f2b(v);
      }
    }
  }
  __syncthreads();

  // ---- GEMM2: up = shift(t) @ Wu^T ; acc2 init = xe + bu ----
  f32x4 acc2[4][4];
  {
    float buv[4];
    #pragma unroll
    for (int nt = 0; nt < 4; ++nt) buv[nt] = bu[wv * 64 + nt * 16 + lr];
    #pragma unroll
    for (int mt = 0; mt < 4; ++mt) {
      #pragma unroll
      for (int nt = 0; nt < 4; ++nt) {
        acc2[mt][nt][0] = b2f(res[mt][nt][0] & 0xffffu) + buv[nt];
        acc2[mt][nt][1] = b2f(res[mt][nt][0] >> 16)     + buv[nt];
        acc2[mt][nt][2] = b2f(res[mt][nt][1] & 0xffffu) + buv[nt];
        acc2[mt][nt][3] = b2f(res[mt][nt][1] >> 16)     + buv[nt];
      }
    }
  }

  #pragma unroll 2
  for (int ks = 0; ks < 8; ++ks) {
    short8 bf[4];
    #pragma unroll
    for (int nt = 0; nt < 4; ++nt)
      bf[nt] = *(const short8*)(wubase + nt * 16 * C_DIM + ks * 32);
    const int g = ks >> 1;              // channel group (64-wide), uniform per ks
    const int dd = ((g & 1) ? -1 : 1) * ((g & 2) ? 8 : 1);
    const int kb = ks * 64 + lg * 16;
    short8 af[4];
    #pragma unroll
    for (int mt = 0; mt < 4; ++mt) {
      int m = mt * 16 + lr;
      int pos = (g & 2) ? (m >> 3) : (m & 7);
      bool ok = (g & 1) ? (pos > 0) : (pos < 7);
      int ms = m + dd;
      ms = ms < 0 ? 0 : (ms > 63 ? 63 : ms);   // safe address, result masked
      short8 v = *(const short8*)((const char*)buf + ms * 512 + (kb ^ ((ms & 7) << 4)));
      const short8 zed = {0, 0, 0, 0, 0, 0, 0, 0};
      af[mt] = ok ? v : zed;
    }
    #pragma unroll
    for (int mt = 0; mt < 4; ++mt)
      #pragma unroll
      for (int nt = 0; nt < 4; ++nt)
        acc2[mt][nt] = __builtin_amdgcn_mfma_f32_16x16x32_bf16(af[mt], bf[nt], acc2[mt][nt], 0, 0, 0);
  }

  // ---- epilogue 2: out = acc2 (already includes xe + bu) ----
  const size_t obase = (size_t)bk * WTOK * C_DIM;
  #pragma unroll
  for (int nt = 0; nt < 4; ++nt) {
    int c = wv * 64 + nt * 16 + lr;
    #pragma unroll
    for (int mt = 0; mt < 4; ++mt) {
      #pragma unroll
      for (int r = 0; r < 4; ++r) {
        int m = mt * 16 + lg * 4 + r;
        out[obase + (size_t)m * C_DIM + c] = acc2[mt][nt][r];
      }
    }
  }
}

// ---------------- launch ----------------
extern "C" void kernel_launch(void* const* d_in, const int* in_sizes, int n_in,
                              void* d_out, int out_size, void* d_ws, size_t ws_size,
                              hipStream_t stream) {
  const float* z  = (const float*)d_in[0];
  const float* x  = (const float*)d_in[1];
  const float* Wd = (const float*)d_in[2];
  const float* bd = (const float*)d_in[3];
  const float* Wu = (const float*)d_in[4];
  const float* bu = (const float*)d_in[5];
  float* out = (float*)d_out;

  char* ws = (char*)d_ws;
  unsigned short* Wdb = (unsigned short*)(ws);            // 131072 B
  unsigned short* Wub = (unsigned short*)(ws + 131072);   // 131072 B
  float* zpart = (float*)(ws + 262144);                   // 256 KB (32*8*256 f32)
  float* score = (float*)(ws + 524288);                   // 8 KB

  hipLaunchKernelGGL(prep_kernel, dim3(320), dim3(256), 0, stream, Wd, Wu, Wdb, Wub, z, zpart);
  hipLaunchKernelGGL(winscore_kernel, dim3(B_SZ * NWIN), dim3(256), 0, stream, x, zpart, score);
  hipLaunchKernelGGL(fused_win, dim3(B_SZ * TOPK_K), dim3(256), 0, stream,
                     x, score, Wdb, Wub, bd, bu, out);
}

// Round 5
// 82.461 us; speedup vs baseline: 1.9649x; 1.1562x over previous
//
#include <hip/hip_runtime.h>
#include <hip/hip_bf16.h>

#define C_DIM 256
#define B_SZ 32
#define NS 4096
#define NT_Z 256
#define TOPK_K 32
#define NWIN 64
#define WTOK 64

typedef __attribute__((ext_vector_type(8))) short short8;
typedef __attribute__((ext_vector_type(4))) float f32x4;

static __device__ inline unsigned short f2b(float f) {
  union { float f; unsigned int u; } x; x.f = f;
  unsigned int u = x.u;
  return (unsigned short)((u + 0x7FFFu + ((u >> 16) & 1u)) >> 16);
}
static __device__ inline float b2f(unsigned int h16) {   // low 16 bits = bf16
  union { unsigned int u; float f; } x; x.u = h16 << 16;
  return x.f;
}

// ---------------- kernel 1: weights f32->bf16 (vectorized) + z_max partials -
__global__ void prep_kernel(const float* __restrict__ Wd, const float* __restrict__ Wu,
                            unsigned short* __restrict__ Wdb, unsigned short* __restrict__ Wub,
                            const float* __restrict__ z, float* __restrict__ zpart) {
  int blk = blockIdx.x;
  if (blk < 64) {
    int i = blk * 256 + threadIdx.x;     // float4 id, 16384 per matrix
    float4 a = ((const float4*)Wd)[i];
    float4 c = ((const float4*)Wu)[i];
    ushort4 ha, hc;
    ha.x = f2b(a.x); ha.y = f2b(a.y); ha.z = f2b(a.z); ha.w = f2b(a.w);
    hc.x = f2b(c.x); hc.y = f2b(c.y); hc.z = f2b(c.z); hc.w = f2b(c.w);
    ((ushort4*)Wdb)[i] = ha;
    ((ushort4*)Wub)[i] = hc;
  } else {
    int i = blk - 64;                    // 0..255
    int b = i >> 3, ch = i & 7;
    int c = threadIdx.x;
    const float* p = z + ((size_t)b * NT_Z + ch * 32) * C_DIM + c;
    float m = p[0];
    for (int n = 1; n < 32; ++n) m = fmaxf(m, p[(size_t)n * C_DIM]);
    zpart[(size_t)i * C_DIM + c] = m;
  }
}

// ---------------- kernel 2: window scores (+ zmax final reduce) -------------
__global__ __launch_bounds__(256) void winscore_kernel(const float* __restrict__ x,
                                                       const float* __restrict__ zpart,
                                                       float* __restrict__ score) {
  int b = blockIdx.x >> 6;
  int w = blockIdx.x & 63;
  int wy = w >> 3, wx = w & 7;

  __shared__ float zs[C_DIM];
  {
    float m = zpart[(size_t)(b * 8) * C_DIM + threadIdx.x];
    #pragma unroll
    for (int ch = 1; ch < 8; ++ch)
      m = fmaxf(m, zpart[(size_t)(b * 8 + ch) * C_DIM + threadIdx.x]);
    zs[threadIdx.x] = m;
  }
  __syncthreads();

  int wv = threadIdx.x >> 6;
  int ln = threadIdx.x & 63;

  float a0 = 0.f, a1 = 0.f, a2 = 0.f, a3 = 0.f;
  for (int t = 0; t < 16; ++t) {
    int tok = wv * 16 + t;
    int iy = tok >> 3, ix = tok & 7;
    int n = (wy * 8 + iy) * 64 + wx * 8 + ix;
    const float4 v = *(const float4*)(x + ((size_t)b * NS + n) * C_DIM + ln * 4);
    a0 += v.x; a1 += v.y; a2 += v.z; a3 += v.w;
  }
  const float4 z4 = ((const float4*)zs)[ln];
  float p = a0 * z4.x + a1 * z4.y + a2 * z4.z + a3 * z4.w;
  for (int off = 32; off >= 1; off >>= 1) p += __shfl_xor(p, off);

  __shared__ float wsum[4];
  if (ln == 0) wsum[wv] = p;
  __syncthreads();
  if (threadIdx.x == 0) score[blockIdx.x] = wsum[0] + wsum[1] + wsum[2] + wsum[3];
}

// ---------------- kernel 3: fused topk + gather + GEMM1 + shift + GEMM2 ----
// one block per (b,k).  TWO 32KB LDS buffers (xe persists; t separate) -> no
// res-capture phase; residual read in epilogue 2.  Weights fully hoisted into
// registers (32 short8 each GEMM), issued where latency hides under
// conversion / barriers.  2 blocks/CU (LDS-limited), 1024 grid = 2 even rounds.
// XOR swizzle: byte_in_row ^= (row & 7) << 4.
__global__ __launch_bounds__(256, 2) void fused_win(
    const float* __restrict__ x, const float* __restrict__ score,
    const unsigned short* __restrict__ Wdb, const unsigned short* __restrict__ Wub,
    const float* __restrict__ bd, const float* __restrict__ bu,
    float* __restrict__ out)
{
  __shared__ unsigned short xe_s[WTOK * C_DIM];  // 32 KB, persists whole kernel
  __shared__ unsigned short t_s[WTOK * C_DIM];   // 32 KB
  __shared__ float sc[NWIN];
  __shared__ int wsel_s;

  const int bk = blockIdx.x;
  const int b = bk >> 5;
  const int kk = bk & 31;
  const int tid = threadIdx.x;

  // ---- in-block top-k rank select (reproduces jax.lax.top_k order) ----
  if (tid < NWIN) sc[tid] = score[b * NWIN + tid];
  __syncthreads();
  if (tid < NWIN) {
    float v = sc[tid];
    int rank = 0;
    #pragma unroll
    for (int j = 0; j < NWIN; ++j) {
      float sj = sc[j];
      rank += (sj > v) || (sj == v && j < tid);
    }
    if (rank == kk) wsel_s = tid;
  }
  __syncthreads();
  const int wsel = wsel_s;
  const int wy = wsel >> 3, wx = wsel & 7;

  const int wv = tid >> 6;
  const int ln = tid & 63;
  const int lr = ln & 15;   // A-row / B-col / D-col
  const int lg = ln >> 4;   // k-subgroup

  const unsigned short* wdbase = Wdb + ((wv * 4) * 16 + lr) * C_DIM + lg * 8;
  const unsigned short* wubase = Wub + ((wv * 4) * 16 + lr) * C_DIM + lg * 8;

  // ---- issue GEMM1 weights first (no deps; land during staging) ----
  short8 wreg[8][4];
  #pragma unroll
  for (int ks = 0; ks < 8; ++ks)
    #pragma unroll
    for (int nt = 0; nt < 4; ++nt)
      wreg[ks][nt] = *(const short8*)(wdbase + nt * 16 * C_DIM + ks * 32);

  // ---- stage xe: all 16 loads in flight, then convert+write ----
  {
    const int c4 = tid & 63;        // float4 column, constant per thread
    const int m0 = tid >> 6;        // starting row
    const float* xb = x + (size_t)b * NS * C_DIM + c4 * 4;
    float4 xv[16];
    #pragma unroll
    for (int i = 0; i < 16; ++i) {
      int m = m0 + i * 4;
      int n = (wy * 8 + (m >> 3)) * 64 + wx * 8 + (m & 7);
      xv[i] = *(const float4*)(xb + (size_t)n * C_DIM);
    }
    #pragma unroll
    for (int i = 0; i < 16; ++i) {
      int m = m0 + i * 4;
      ushort4 h;
      h.x = f2b(xv[i].x); h.y = f2b(xv[i].y); h.z = f2b(xv[i].z); h.w = f2b(xv[i].w);
      int byteoff = m * 512 + ((c4 * 8) ^ ((m & 7) << 4));
      *(ushort4*)((char*)xe_s + byteoff) = h;
    }
  }
  __syncthreads();

  // ---- GEMM1: t = xe @ Wd^T (weights already in regs) ----
  f32x4 acc[4][4];
  #pragma unroll
  for (int a = 0; a < 4; ++a)
    #pragma unroll
    for (int n2 = 0; n2 < 4; ++n2) acc[a][n2] = (f32x4){0.f, 0.f, 0.f, 0.f};

  #pragma unroll
  for (int ks = 0; ks < 8; ++ks) {
    const int kb = ks * 64 + lg * 16;
    short8 af[4];
    #pragma unroll
    for (int mt = 0; mt < 4; ++mt) {
      int m = mt * 16 + lr;
      af[mt] = *(const short8*)((const char*)xe_s + m * 512 + (kb ^ ((m & 7) << 4)));
    }
    #pragma unroll
    for (int mt = 0; mt < 4; ++mt)
      #pragma unroll
      for (int nt = 0; nt < 4; ++nt)
        acc[mt][nt] = __builtin_amdgcn_mfma_f32_16x16x32_bf16(af[mt], wreg[ks][nt], acc[mt][nt], 0, 0, 0);
  }

  // ---- epilogue 1: t = acc + bd -> bf16 -> t_s (swizzled); acc dies ----
  #pragma unroll
  for (int nt = 0; nt < 4; ++nt) {
    int o = wv * 64 + nt * 16 + lr;
    float bdv = bd[o];
    #pragma unroll
    for (int mt = 0; mt < 4; ++mt) {
      #pragma unroll
      for (int r = 0; r < 4; ++r) {
        int m = mt * 16 + lg * 4 + r;
        float v = acc[mt][nt][r] + bdv;
        *(unsigned short*)((char*)t_s + m * 512 + ((o * 2) ^ ((m & 7) << 4))) = f2b(v);
      }
    }
  }

  // ---- issue GEMM2 weights (land under the barrier) ----
  short8 wreg2[8][4];
  #pragma unroll
  for (int ks = 0; ks < 8; ++ks)
    #pragma unroll
    for (int nt = 0; nt < 4; ++nt)
      wreg2[ks][nt] = *(const short8*)(wubase + nt * 16 * C_DIM + ks * 32);

  __syncthreads();

  // ---- GEMM2: up = shift(t) @ Wu^T ----
  f32x4 acc2[4][4];
  #pragma unroll
  for (int a = 0; a < 4; ++a)
    #pragma unroll
    for (int n2 = 0; n2 < 4; ++n2) acc2[a][n2] = (f32x4){0.f, 0.f, 0.f, 0.f};

  #pragma unroll
  for (int ks = 0; ks < 8; ++ks) {
    const int g = ks >> 1;              // channel group (64-wide), uniform per ks
    const int dd = ((g & 1) ? -1 : 1) * ((g & 2) ? 8 : 1);
    const int kb = ks * 64 + lg * 16;
    short8 af[4];
    #pragma unroll
    for (int mt = 0; mt < 4; ++mt) {
      int m = mt * 16 + lr;
      int pos = (g & 2) ? (m >> 3) : (m & 7);
      bool ok = (g & 1) ? (pos > 0) : (pos < 7);
      int ms = m + dd;
      ms = ms < 0 ? 0 : (ms > 63 ? 63 : ms);   // safe address, result masked
      short8 v = *(const short8*)((const char*)t_s + ms * 512 + (kb ^ ((ms & 7) << 4)));
      const short8 zed = {0, 0, 0, 0, 0, 0, 0, 0};
      af[mt] = ok ? v : zed;
    }
    #pragma unroll
    for (int mt = 0; mt < 4; ++mt)
      #pragma unroll
      for (int nt = 0; nt < 4; ++nt)
        acc2[mt][nt] = __builtin_amdgcn_mfma_f32_16x16x32_bf16(af[mt], wreg2[ks][nt], acc2[mt][nt], 0, 0, 0);
  }

  // ---- epilogue 2: out = xe(residual from LDS) + up + bu ----
  const size_t obase = (size_t)bk * WTOK * C_DIM;
  #pragma unroll
  for (int nt = 0; nt < 4; ++nt) {
    int c = wv * 64 + nt * 16 + lr;
    float buv = bu[c];
    #pragma unroll
    for (int mt = 0; mt < 4; ++mt) {
      #pragma unroll
      for (int r = 0; r < 4; ++r) {
        int m = mt * 16 + lg * 4 + r;
        unsigned int xb =
            *(const unsigned short*)((const char*)xe_s + m * 512 + ((c * 2) ^ ((m & 7) << 4)));
        out[obase + (size_t)m * C_DIM + c] = b2f(xb) + acc2[mt][nt][r] + buv;
      }
    }
  }
}

// ---------------- launch ----------------
extern "C" void kernel_launch(void* const* d_in, const int* in_sizes, int n_in,
                              void* d_out, int out_size, void* d_ws, size_t ws_size,
                              hipStream_t stream) {
  const float* z  = (const float*)d_in[0];
  const float* x  = (const float*)d_in[1];
  const float* Wd = (const float*)d_in[2];
  const float* bd = (const float*)d_in[3];
  const float* Wu = (const float*)d_in[4];
  const float* bu = (const float*)d_in[5];
  float* out = (float*)d_out;

  char* ws = (char*)d_ws;
  unsigned short* Wdb = (unsigned short*)(ws);            // 131072 B
  unsigned short* Wub = (unsigned short*)(ws + 131072);   // 131072 B
  float* zpart = (float*)(ws + 262144);                   // 256 KB (32*8*256 f32)
  float* score = (float*)(ws + 524288);                   // 8 KB

  hipLaunchKernelGGL(prep_kernel, dim3(320), dim3(256), 0, stream, Wd, Wu, Wdb, Wub, z, zpart);
  hipLaunchKernelGGL(winscore_kernel, dim3(B_SZ * NWIN), dim3(256), 0, stream, x, zpart, score);
  hipLaunchKernelGGL(fused_win, dim3(B_SZ * TOPK_K), dim3(256), 0, stream,
                     x, score, Wdb, Wub, bd, bu, out);
}